// Round 9
// baseline (3690.224 us; speedup 1.0000x reference)
//
#include <hip/hip_runtime.h>

#define D 64
#define NEG_INF -9e15f
#define MAXK 16
#define BSH 6                 // bucket = 64 rows
#define BROWS 64
#define MAXNB 2048
#define SCAP 4096             // LDS sort capacity; bucket mean 3413, sigma 58 (+11s)
#define COLSH 9               // coarse col bin = 512 cols
#define COLB 256              // col bins (2^17 >> 9 = 256)

// ---------- Phase 0: relation-space precompute ----------
__global__ void relpre_kernel(const float* __restrict__ fc_W, const float* __restrict__ fc_b,
                              const float* __restrict__ rel_emb,
                              float* __restrict__ w1r, float* __restrict__ w2r,
                              float* __restrict__ br) {
    int r = blockIdx.x;
    int j = threadIdx.x;
    const float* rr = rel_emb + r * D;
    float s1 = 0.f, s2 = 0.f;
    for (int d = 0; d < D; ++d) {
        float rv = rr[d];
        s1 += fc_W[j * D + d] * rv;
        s2 += fc_W[(D + j) * D + d] * rv;
    }
    w1r[r * D + j] = s1;
    w2r[r * D + j] = s2;
    if (j == 0) {
        float sb = 0.f;
        for (int d = 0; d < D; ++d) sb += fc_b[d] * rr[d];
        br[r] = sb;
    }
}

// ---------- Phase 1: GAT item embeddings, K=16 specialized ----------
__global__ void gat16_kernel(const float* __restrict__ item_emb, const float* __restrict__ ent_emb,
                             const int* __restrict__ kg_e, const int* __restrict__ kg_r,
                             const float* __restrict__ w1r, const float* __restrict__ w2r,
                             const float* __restrict__ br,
                             float* __restrict__ x_items, int I, int pad_id) {
    const int K = 16;
    int wave = (blockIdx.x * blockDim.x + threadIdx.x) >> 6;
    int lane = threadIdx.x & 63;
    if (wave >= I) return;
    int i = wave;
    float itemv = item_emb[i * D + lane];
    float entv[16], pp[16], brv[16];
    int eidx_[16];
    #pragma unroll
    for (int k = 0; k < K; ++k) {
        int eidx = kg_e[i * K + k];
        int r = kg_r[i * K + k];
        eidx_[k] = eidx;
        float ev = ent_emb[(long)eidx * D + lane];
        entv[k] = ev;
        pp[k] = itemv * w1r[r * D + lane] + ev * w2r[r * D + lane];
        brv[k] = br[r];
    }
    float e[16];
    #pragma unroll
    for (int k = 0; k < K; ++k) {
        float p = pp[k];
        #pragma unroll
        for (int off = 32; off > 0; off >>= 1) p += __shfl_xor(p, off, 64);
        p += brv[k];
        p = p > 0.f ? p : 0.2f * p;
        if (eidx_[k] == pad_id) p = NEG_INF;
        e[k] = p;
    }
    float m = e[0];
    #pragma unroll
    for (int k = 1; k < K; ++k) m = fmaxf(m, e[k]);
    float s = 0.f;
    float att[16];
    #pragma unroll
    for (int k = 0; k < K; ++k) { att[k] = expf(e[k] - m); s += att[k]; }
    float inv = 1.f / s;
    float o = itemv;
    #pragma unroll
    for (int k = 0; k < K; ++k) o += att[k] * inv * entv[k];
    x_items[(long)i * D + lane] = o;
}

// ---------- Phase 1 fallback: generic K ----------
__global__ void gat_kernel(const float* __restrict__ item_emb, const float* __restrict__ ent_emb,
                           const int* __restrict__ kg_e, const int* __restrict__ kg_r,
                           const float* __restrict__ w1r, const float* __restrict__ w2r,
                           const float* __restrict__ br,
                           float* __restrict__ x_items, int I, int K, int pad_id) {
    int wave = (blockIdx.x * blockDim.x + threadIdx.x) >> 6;
    int lane = threadIdx.x & 63;
    if (wave >= I) return;
    int i = wave;
    float itemv = item_emb[i * D + lane];
    float entv[MAXK];
    float e[MAXK];
    for (int k = 0; k < K; ++k) {
        int eidx = kg_e[i * K + k];
        int r = kg_r[i * K + k];
        float ev = ent_emb[(long)eidx * D + lane];
        entv[k] = ev;
        float p = itemv * w1r[r * D + lane] + ev * w2r[r * D + lane];
        #pragma unroll
        for (int off = 32; off > 0; off >>= 1) p += __shfl_xor(p, off, 64);
        p += br[r];
        p = p > 0.f ? p : 0.2f * p;
        if (eidx == pad_id) p = NEG_INF;
        e[k] = p;
    }
    float m = e[0];
    for (int k = 1; k < K; ++k) m = fmaxf(m, e[k]);
    float s = 0.f;
    float att[MAXK];
    for (int k = 0; k < K; ++k) { att[k] = expf(e[k] - m); s += att[k]; }
    float inv = 1.f / s;
    float o = itemv;
    for (int k = 0; k < K; ++k) o += att[k] * inv * entv[k];
    x_items[(long)i * D + lane] = o;
}

// ---------- init (deferred mode): copy user_emb -> x0 user half ----------
__global__ void copyu_kernel(const float* __restrict__ src, float* __restrict__ dst, int n4) {
    int i = blockIdx.x * blockDim.x + threadIdx.x;
    if (i < n4) ((float4*)dst)[i] = ((const float4*)src)[i];
}

// ---------- init (legacy mode): x users + acc = x ----------
__global__ void init_kernel(const float* __restrict__ user_emb,
                            float* __restrict__ x, float* __restrict__ acc,
                            int UD, int ND) {
    for (int idx = blockIdx.x * blockDim.x + threadIdx.x; idx < ND;
         idx += gridDim.x * blockDim.x) {
        float v = (idx < UD) ? user_emb[idx] : x[idx];
        x[idx] = v;
        acc[idx] = v;
    }
}

// ---------- Mark batch rows for sparse layer 3 ----------
__global__ void mark_kernel(const int* __restrict__ users, const int* __restrict__ items,
                            int* __restrict__ flags, int U, int B) {
    int i = blockIdx.x * blockDim.x + threadIdx.x;
    if (i < B) {
        flags[users[i]] = 1;
        flags[U + items[i]] = 1;
    }
}

// ---------- Bucket histogram (LDS-staged) ----------
__global__ void bhist_kernel(const int* __restrict__ rows, int* __restrict__ bcnt,
                             int n_edges, int NB) {
    __shared__ int h[MAXNB];
    for (int i = threadIdx.x; i < NB; i += blockDim.x) h[i] = 0;
    __syncthreads();
    for (int e = blockIdx.x * blockDim.x + threadIdx.x; e < n_edges;
         e += gridDim.x * blockDim.x)
        atomicAdd(&h[rows[e] >> BSH], 1);
    __syncthreads();
    for (int i = threadIdx.x; i < NB; i += blockDim.x)
        if (h[i]) atomicAdd(&bcnt[i], h[i]);
}

// ---------- Bucket scan (single block, 1024 thr, up to 2048 entries) ----------
__global__ void bscan_kernel(const int* __restrict__ bcnt, int* __restrict__ bstart,
                             int* __restrict__ bfill, int NB, int n_edges) {
    __shared__ int bufA[MAXNB];
    __shared__ int bufB[MAXNB];
    int tid = threadIdx.x;
    int v0 = (tid < NB) ? bcnt[tid] : 0;
    int v1 = (tid + 1024 < NB) ? bcnt[tid + 1024] : 0;
    bufA[tid] = v0;
    bufA[tid + 1024] = v1;
    __syncthreads();
    int* src = bufA;
    int* dst = bufB;
    for (int off = 1; off < MAXNB; off <<= 1) {
        int j0 = tid, j1 = tid + 1024;
        dst[j0] = src[j0] + (j0 >= off ? src[j0 - off] : 0);
        dst[j1] = src[j1] + (j1 >= off ? src[j1 - off] : 0);
        __syncthreads();
        int* t = src; src = dst; dst = t;
    }
    if (tid < NB)        { int ex = src[tid] - v0;        bstart[tid] = ex;        bfill[tid] = ex; }
    if (tid + 1024 < NB) { int ex = src[tid + 1024] - v1; bstart[tid + 1024] = ex; bfill[tid + 1024] = ex; }
    if (tid == 0) bstart[NB] = n_edges;
}

// ---------- Partition: per-block hist -> segment reserve -> direct write ----------
// etmp[pos] = (valbits<<32) | (row&63)<<20 | col   (normal stores: L2 absorbs)
__global__ void part_kernel(const int* __restrict__ rows, const int* __restrict__ cols,
                            const float* __restrict__ vals,
                            int* __restrict__ bfill, long* __restrict__ etmp,
                            int n_edges, int NB) {
    __shared__ int h[MAXNB];
    __shared__ int base[MAXNB];
    __shared__ int off[MAXNB];
    int nb_blocks = gridDim.x;
    int c0 = (int)((long)n_edges * blockIdx.x / nb_blocks);
    int c1 = (int)((long)n_edges * (blockIdx.x + 1) / nb_blocks);
    for (int i = threadIdx.x; i < NB; i += blockDim.x) { h[i] = 0; off[i] = 0; }
    __syncthreads();
    for (int e = c0 + threadIdx.x; e < c1; e += blockDim.x)
        atomicAdd(&h[rows[e] >> BSH], 1);
    __syncthreads();
    for (int i = threadIdx.x; i < NB; i += blockDim.x)
        if (h[i]) base[i] = atomicAdd(&bfill[i], h[i]);
    __syncthreads();
    for (int e = c0 + threadIdx.x; e < c1; e += blockDim.x) {
        int r = rows[e];
        int b = r >> BSH;
        int pos = base[b] + atomicAdd(&off[b], 1);
        etmp[pos] = ((long)(unsigned)__float_as_int(vals[e]) << 32)
                  | (unsigned)(cols[e] | ((r & (BROWS - 1)) << 20));
    }
}

// ---------- In-bucket COL counting sort (pass A only) ----------
// Output: bucket edges in ascending coarse-col order (row order irrelevant --
// the LDS-accumulator spmv keys on the 6-bit local row in the payload).
// This makes every block's gather stream sweep x in the same direction.
__global__ __launch_bounds__(256) void
sorta_kernel(const long* __restrict__ etmp, const int* __restrict__ bstart,
             long* __restrict__ edges) {
    __shared__ long obuf[SCAP];
    __shared__ int hc[COLB];
    __shared__ int oc[COLB];
    __shared__ int sc[COLB];
    int b = blockIdx.x;
    int s = bstart[b];
    int t = bstart[b + 1];
    int m = t - s;
    int tid = threadIdx.x;
    hc[tid] = 0; oc[tid] = 0;              // COLB == blockDim == 256
    __syncthreads();
    if (m <= SCAP) {
        for (int i = tid; i < m; i += 256)
            atomicAdd(&hc[((int)etmp[s + i] & 0xFFFFF) >> COLSH], 1);
        __syncthreads();
        int v = hc[tid];
        sc[tid] = v;
        __syncthreads();
        for (int o = 1; o < COLB; o <<= 1) {
            int u = (tid >= o) ? sc[tid - o] : 0;
            __syncthreads();
            sc[tid] += u;
            __syncthreads();
        }
        hc[tid] = sc[tid] - v;             // exclusive offsets
        __syncthreads();
        for (int i = tid; i < m; i += 256) {
            long p = etmp[s + i];          // L2-hot second read
            int bin = ((int)p & 0xFFFFF) >> COLSH;
            int pos = hc[bin] + atomicAdd(&oc[bin], 1);
            obuf[pos] = p;
        }
        __syncthreads();
        for (int i = tid; i < m; i += 256) edges[s + i] = obuf[i];
    } else {
        // capacity fallback: copy unsorted (perf only, still bucket-grouped)
        for (int i = tid; i < m; i += 256) edges[s + i] = etmp[s + i];
    }
}

// ---------- Phase 2b: bucketed SpMV, LDS accumulate, col-ordered sweep ----------
// One block per 64-row bucket; 16KB tile -> 8 blocks/CU (32 waves, full occ);
// all 1172 blocks co-resident and sweeping cols in the same order -> the
// concurrent gather window stays L2-resident. Edge loads are nontemporal so
// the 32MB stream doesn't evict the x window. FLAGS=1: skip edges whose
// local row is unflagged (sparse layer 3) -- wave-uniform branch.
template<int FLAGS>
__global__ __launch_bounds__(256) void
spmv_lds_kernel(const long* __restrict__ edges, const int* __restrict__ bstart,
                const float* __restrict__ x, float* __restrict__ nxt,
                float* __restrict__ acc, const int* __restrict__ flags, int N) {
    __shared__ float tile[BROWS * D];      // 16 KB
    __shared__ unsigned char fl[BROWS];
    int b = blockIdx.x;
    int tid = threadIdx.x;
    int row0 = b << BSH;
    for (int i = tid; i < BROWS * D; i += 256) tile[i] = 0.f;
    if (FLAGS && tid < BROWS)
        fl[tid] = (row0 + tid < N) ? (unsigned char)flags[row0 + tid] : 0;
    __syncthreads();
    int s = bstart[b];
    int t = bstart[b + 1];
    int lane = tid & 63;
    int w = tid >> 6;                      // 4 waves
    int m = t - s;
    int full = m >> 5;                     // groups of 32 (8 per wave)
    for (int g = 0; g < full; ++g) {
        int e = s + (g << 5) + (w << 3);
        if (!FLAGS) {
            long q[8];
            float gv[8];
            #pragma unroll
            for (int j = 0; j < 8; ++j) q[j] = __builtin_nontemporal_load(&edges[e + j]);
            #pragma unroll
            for (int j = 0; j < 8; ++j)
                gv[j] = x[(long)((int)q[j] & 0xFFFFF) * D + lane];
            #pragma unroll
            for (int j = 0; j < 8; ++j) {
                int r = ((int)q[j] >> 20) & (BROWS - 1);
                unsafeAtomicAdd(&tile[(r << 6) + lane],
                                __int_as_float((int)(q[j] >> 32)) * gv[j]);
            }
        } else {
            #pragma unroll
            for (int j = 0; j < 8; ++j) {
                long q = __builtin_nontemporal_load(&edges[e + j]);
                int r = ((int)q >> 20) & (BROWS - 1);
                if (fl[r]) {
                    float gv = x[(long)((int)q & 0xFFFFF) * D + lane];
                    unsafeAtomicAdd(&tile[(r << 6) + lane],
                                    __int_as_float((int)(q >> 32)) * gv);
                }
            }
        }
    }
    // tail (< 32 edges)
    int e0 = s + (full << 5) + (w << 3);
    int e1 = (e0 + 8 < t) ? e0 + 8 : t;
    for (int e = e0; e < e1; ++e) {
        long q = __builtin_nontemporal_load(&edges[e]);
        int r = ((int)q >> 20) & (BROWS - 1);
        if (!FLAGS || fl[r]) {
            float gv = x[(long)((int)q & 0xFFFFF) * D + lane];
            unsafeAtomicAdd(&tile[(r << 6) + lane],
                            __int_as_float((int)(q >> 32)) * gv);
        }
    }
    __syncthreads();
    // flush: coalesced, once per layer
    for (int i = tid; i < BROWS * D; i += 256) {
        int row = row0 + (i >> 6);
        if (row >= N) break;
        long o = ((long)row0 << 6) + i;
        float sv = tile[i];
        if (acc) { nxt[o] = sv; acc[o] += sv; }
        else __builtin_nontemporal_store(sv, &nxt[o]);
    }
}

// ---------- Phase 3: gamma = dot of layer-mean embeddings ----------
__global__ void dot_kernel(const float* __restrict__ x0, const float* __restrict__ x1,
                           const float* __restrict__ x2, const float* __restrict__ x3,
                           const float* __restrict__ acc,
                           const int* __restrict__ users, const int* __restrict__ items,
                           float* __restrict__ out, int U, int B) {
    int wave = (blockIdx.x * blockDim.x + threadIdx.x) >> 6;
    int lane = threadIdx.x & 63;
    if (wave >= B) return;
    long ou = (long)users[wave] * D + lane;
    long oi = (long)(U + items[wave]) * D + lane;
    float su, si;
    if (acc) {
        su = acc[ou];
        si = acc[oi];
    } else {
        su = x0[ou] + x1[ou] + x2[ou] + x3[ou];
        si = x0[oi] + x1[oi] + x2[oi] + x3[oi];
    }
    float p = su * si;
    #pragma unroll
    for (int off = 32; off > 0; off >>= 1) p += __shfl_xor(p, off, 64);
    if (lane == 0) out[wave] = p * 0.0625f;
}

extern "C" void kernel_launch(void* const* d_in, const int* in_sizes, int n_in,
                              void* d_out, int out_size, void* d_ws, size_t ws_size,
                              hipStream_t stream) {
    const int*   users    = (const int*)  d_in[0];
    const int*   items    = (const int*)  d_in[1];
    const int*   g_rows   = (const int*)  d_in[2];
    const int*   g_cols   = (const int*)  d_in[3];
    const float* g_vals   = (const float*)d_in[4];
    const float* user_emb = (const float*)d_in[5];
    const float* item_emb = (const float*)d_in[6];
    const float* ent_emb  = (const float*)d_in[7];
    const float* rel_emb  = (const float*)d_in[8];
    const int*   kg_e     = (const int*)  d_in[9];
    const int*   kg_r     = (const int*)  d_in[10];
    const float* fc_W     = (const float*)d_in[11];
    const float* fc_b     = (const float*)d_in[12];
    float* out = (float*)d_out;

    int B       = in_sizes[0];
    int n_edges = in_sizes[2];
    int U       = in_sizes[5] / D;
    int I       = in_sizes[6] / D;
    int NE1     = in_sizes[7] / D;   // E_ENT + 1
    int NR      = in_sizes[8] / D;   // R + 1
    int K       = in_sizes[9] / I;
    int N  = U + I;
    int ND = N * D;
    int NB = (N + BROWS - 1) >> BSH;   // 1172 buckets (<= MAXNB)

    // deferred-acc mode needs 4 layer buffers; legacy needs 3 (x,y,acc)
    size_t small = (size_t)(2 * NR * D + NR + 3 * (NB + 1) + N) * 4 + 8192;
    size_t need_def = 4ul * ND * 4 + (size_t)n_edges * 8 + small;
    int deferred = (need_def <= ws_size);

    char* basep = (char*)d_ws;
    size_t woff = 0;
    auto alloc = [&](size_t bytes) -> char* {
        char* p = basep + woff;
        woff = (woff + bytes + 255) & ~(size_t)255;
        return p;
    };

    float *x0, *x1, *x2, *x3, *acc;
    long* etmp;
    if (deferred) {
        x0 = (float*)alloc((size_t)ND * 4);
        x1 = (float*)alloc((size_t)ND * 4);
        x2 = (float*)alloc((size_t)ND * 4);
        x3 = (float*)alloc((size_t)ND * 4);
        acc = nullptr;
        etmp = (long*)x2;               // x2+x3 span 38.4MB >= 32MB; build precedes layers
    } else {
        x0 = (float*)alloc((size_t)ND * 4);
        x1 = (float*)alloc((size_t)ND * 4);
        x2 = x0; x3 = x1;               // ping-pong
        acc = (float*)alloc((size_t)ND * 4);
        etmp = (long*)x0;               // x0+x1 span
    }
    float* w1r    = (float*)alloc((size_t)NR * D * 4);
    float* w2r    = (float*)alloc((size_t)NR * D * 4);
    float* br     = (float*)alloc((size_t)NR * 4);
    int*   bcnt   = (int*)  alloc((size_t)(NB + 1) * 4);
    int*   bstart = (int*)  alloc((size_t)(NB + 1) * 4);
    int*   bfill  = (int*)  alloc((size_t)(NB + 1) * 4);
    int*   flags  = (int*)  alloc((size_t)N * 4);
    long*  edges  = (long*) alloc((size_t)n_edges * 8);

    // ---- build: bucket partition + in-bucket col sort (etmp in layer space) ----
    hipMemsetAsync(bcnt, 0, (size_t)(NB + 1) * 4, stream);
    bhist_kernel<<<1024, 256, 0, stream>>>(g_rows, bcnt, n_edges, NB);
    bscan_kernel<<<1, 1024, 0, stream>>>(bcnt, bstart, bfill, NB, n_edges);
    part_kernel<<<1024, 256, 0, stream>>>(g_rows, g_cols, g_vals, bfill, etmp, n_edges, NB);
    sorta_kernel<<<NB, 256, 0, stream>>>(etmp, bstart, edges);

    // ---- batch-row flags for sparse layer 3 ----
    hipMemsetAsync(flags, 0, (size_t)N * 4, stream);
    mark_kernel<<<(B + 255) / 256, 256, 0, stream>>>(users, items, flags, U, B);

    // Phase 0 + 1: GAT
    relpre_kernel<<<NR, D, 0, stream>>>(fc_W, fc_b, rel_emb, w1r, w2r, br);
    if (K == 16) {
        gat16_kernel<<<(I + 3) / 4, 256, 0, stream>>>(item_emb, ent_emb, kg_e, kg_r,
                                                      w1r, w2r, br,
                                                      x0 + (long)U * D, I, NE1 - 1);
    } else {
        gat_kernel<<<(I + 3) / 4, 256, 0, stream>>>(item_emb, ent_emb, kg_e, kg_r,
                                                    w1r, w2r, br,
                                                    x0 + (long)U * D, I, K, NE1 - 1);
    }

    // Phase 2a: user half of x0 (+ acc init in legacy mode)
    if (deferred) {
        int n4 = U * D / 4;
        copyu_kernel<<<(n4 + 255) / 256, 256, 0, stream>>>(user_emb, x0, n4);
    } else {
        init_kernel<<<2048, 256, 0, stream>>>(user_emb, x0, acc, U * D, ND);
    }

    // Phase 2b: LightGCN layers -- bucketed LDS spmv, layer 3 flag-sparse
    spmv_lds_kernel<0><<<NB, 256, 0, stream>>>(edges, bstart, x0, x1, acc, nullptr, N);
    spmv_lds_kernel<0><<<NB, 256, 0, stream>>>(edges, bstart, x1, x2, acc, nullptr, N);
    spmv_lds_kernel<1><<<NB, 256, 0, stream>>>(edges, bstart, x2, x3, acc, flags, N);

    // Phase 3: batch dot
    dot_kernel<<<(B + 3) / 4, 256, 0, stream>>>(x0, x1, x2, x3, acc, users, items, out, U, B);
}

// Round 10
// 479.340 us; speedup vs baseline: 7.6986x; 7.6986x over previous
//
#include <hip/hip_runtime.h>

#define D 64
#define NEG_INF -9e15f
#define MAXK 16
#define BSH 6                 // bucket = 64 rows
#define BROWS 64
#define MAXNB 2048
#define SCAP 4096             // LDS sort capacity; bucket mean 3413, sigma 58 (+11s)

// ---------- Phase 0: relation-space precompute ----------
__global__ void relpre_kernel(const float* __restrict__ fc_W, const float* __restrict__ fc_b,
                              const float* __restrict__ rel_emb,
                              float* __restrict__ w1r, float* __restrict__ w2r,
                              float* __restrict__ br) {
    int r = blockIdx.x;
    int j = threadIdx.x;
    const float* rr = rel_emb + r * D;
    float s1 = 0.f, s2 = 0.f;
    for (int d = 0; d < D; ++d) {
        float rv = rr[d];
        s1 += fc_W[j * D + d] * rv;
        s2 += fc_W[(D + j) * D + d] * rv;
    }
    w1r[r * D + j] = s1;
    w2r[r * D + j] = s2;
    if (j == 0) {
        float sb = 0.f;
        for (int d = 0; d < D; ++d) sb += fc_b[d] * rr[d];
        br[r] = sb;
    }
}

// ---------- Phase 1: GAT item embeddings, K=16 specialized ----------
__global__ void gat16_kernel(const float* __restrict__ item_emb, const float* __restrict__ ent_emb,
                             const int* __restrict__ kg_e, const int* __restrict__ kg_r,
                             const float* __restrict__ w1r, const float* __restrict__ w2r,
                             const float* __restrict__ br,
                             float* __restrict__ x_items, int I, int pad_id) {
    const int K = 16;
    int wave = (blockIdx.x * blockDim.x + threadIdx.x) >> 6;
    int lane = threadIdx.x & 63;
    if (wave >= I) return;
    int i = wave;
    float itemv = item_emb[i * D + lane];
    float entv[16], pp[16], brv[16];
    int eidx_[16];
    #pragma unroll
    for (int k = 0; k < K; ++k) {
        int eidx = kg_e[i * K + k];
        int r = kg_r[i * K + k];
        eidx_[k] = eidx;
        float ev = ent_emb[(long)eidx * D + lane];
        entv[k] = ev;
        pp[k] = itemv * w1r[r * D + lane] + ev * w2r[r * D + lane];
        brv[k] = br[r];
    }
    float e[16];
    #pragma unroll
    for (int k = 0; k < K; ++k) {
        float p = pp[k];
        #pragma unroll
        for (int off = 32; off > 0; off >>= 1) p += __shfl_xor(p, off, 64);
        p += brv[k];
        p = p > 0.f ? p : 0.2f * p;
        if (eidx_[k] == pad_id) p = NEG_INF;
        e[k] = p;
    }
    float m = e[0];
    #pragma unroll
    for (int k = 1; k < K; ++k) m = fmaxf(m, e[k]);
    float s = 0.f;
    float att[16];
    #pragma unroll
    for (int k = 0; k < K; ++k) { att[k] = expf(e[k] - m); s += att[k]; }
    float inv = 1.f / s;
    float o = itemv;
    #pragma unroll
    for (int k = 0; k < K; ++k) o += att[k] * inv * entv[k];
    x_items[(long)i * D + lane] = o;
}

// ---------- Phase 1 fallback: generic K ----------
__global__ void gat_kernel(const float* __restrict__ item_emb, const float* __restrict__ ent_emb,
                           const int* __restrict__ kg_e, const int* __restrict__ kg_r,
                           const float* __restrict__ w1r, const float* __restrict__ w2r,
                           const float* __restrict__ br,
                           float* __restrict__ x_items, int I, int K, int pad_id) {
    int wave = (blockIdx.x * blockDim.x + threadIdx.x) >> 6;
    int lane = threadIdx.x & 63;
    if (wave >= I) return;
    int i = wave;
    float itemv = item_emb[i * D + lane];
    float entv[MAXK];
    float e[MAXK];
    for (int k = 0; k < K; ++k) {
        int eidx = kg_e[i * K + k];
        int r = kg_r[i * K + k];
        float ev = ent_emb[(long)eidx * D + lane];
        entv[k] = ev;
        float p = itemv * w1r[r * D + lane] + ev * w2r[r * D + lane];
        #pragma unroll
        for (int off = 32; off > 0; off >>= 1) p += __shfl_xor(p, off, 64);
        p += br[r];
        p = p > 0.f ? p : 0.2f * p;
        if (eidx == pad_id) p = NEG_INF;
        e[k] = p;
    }
    float m = e[0];
    for (int k = 1; k < K; ++k) m = fmaxf(m, e[k]);
    float s = 0.f;
    float att[MAXK];
    for (int k = 0; k < K; ++k) { att[k] = expf(e[k] - m); s += att[k]; }
    float inv = 1.f / s;
    float o = itemv;
    for (int k = 0; k < K; ++k) o += att[k] * inv * entv[k];
    x_items[(long)i * D + lane] = o;
}

// ---------- init (deferred mode): copy user_emb -> x0 user half ----------
__global__ void copyu_kernel(const float* __restrict__ src, float* __restrict__ dst, int n4) {
    int i = blockIdx.x * blockDim.x + threadIdx.x;
    if (i < n4) ((float4*)dst)[i] = ((const float4*)src)[i];
}

// ---------- init (legacy mode): x users + acc = x ----------
__global__ void init_kernel(const float* __restrict__ user_emb,
                            float* __restrict__ x, float* __restrict__ acc,
                            int UD, int ND) {
    for (int idx = blockIdx.x * blockDim.x + threadIdx.x; idx < ND;
         idx += gridDim.x * blockDim.x) {
        float v = (idx < UD) ? user_emb[idx] : x[idx];
        x[idx] = v;
        acc[idx] = v;
    }
}

// ---------- Mark + compact batch rows for sparse layer 3 ----------
// flags: dedup guard; rowlist: dense unique batch-row list; nlist: counter.
__global__ void mark_kernel(const int* __restrict__ users, const int* __restrict__ items,
                            int* __restrict__ flags, int* __restrict__ rowlist,
                            int* __restrict__ nlist, int U, int B) {
    int i = blockIdx.x * blockDim.x + threadIdx.x;
    if (i >= B) return;
    int r1 = users[i];
    if (atomicExch(&flags[r1], 1) == 0) rowlist[atomicAdd(nlist, 1)] = r1;
    int r2 = U + items[i];
    if (atomicExch(&flags[r2], 1) == 0) rowlist[atomicAdd(nlist, 1)] = r2;
}

// ---------- Bucket histogram (LDS-staged) ----------
__global__ void bhist_kernel(const int* __restrict__ rows, int* __restrict__ bcnt,
                             int n_edges, int NB) {
    __shared__ int h[MAXNB];
    for (int i = threadIdx.x; i < NB; i += blockDim.x) h[i] = 0;
    __syncthreads();
    for (int e = blockIdx.x * blockDim.x + threadIdx.x; e < n_edges;
         e += gridDim.x * blockDim.x)
        atomicAdd(&h[rows[e] >> BSH], 1);
    __syncthreads();
    for (int i = threadIdx.x; i < NB; i += blockDim.x)
        if (h[i]) atomicAdd(&bcnt[i], h[i]);
}

// ---------- Bucket scan (single block, 1024 thr, up to 2048 entries) ----------
__global__ void bscan_kernel(const int* __restrict__ bcnt, int* __restrict__ bstart,
                             int* __restrict__ bfill, int NB, int n_edges) {
    __shared__ int bufA[MAXNB];
    __shared__ int bufB[MAXNB];
    int tid = threadIdx.x;
    int v0 = (tid < NB) ? bcnt[tid] : 0;
    int v1 = (tid + 1024 < NB) ? bcnt[tid + 1024] : 0;
    bufA[tid] = v0;
    bufA[tid + 1024] = v1;
    __syncthreads();
    int* src = bufA;
    int* dst = bufB;
    for (int off = 1; off < MAXNB; off <<= 1) {
        int j0 = tid, j1 = tid + 1024;
        dst[j0] = src[j0] + (j0 >= off ? src[j0 - off] : 0);
        dst[j1] = src[j1] + (j1 >= off ? src[j1 - off] : 0);
        __syncthreads();
        int* t = src; src = dst; dst = t;
    }
    if (tid < NB)        { int ex = src[tid] - v0;        bstart[tid] = ex;        bfill[tid] = ex; }
    if (tid + 1024 < NB) { int ex = src[tid + 1024] - v1; bstart[tid + 1024] = ex; bfill[tid + 1024] = ex; }
    if (tid == 0) bstart[NB] = n_edges;
}

// ---------- Partition: per-block hist -> segment reserve -> direct write ----------
// etmp[pos] = (valbits<<32) | (row&63)<<20 | col   (normal stores: L2 absorbs)
__global__ void part_kernel(const int* __restrict__ rows, const int* __restrict__ cols,
                            const float* __restrict__ vals,
                            int* __restrict__ bfill, long* __restrict__ etmp,
                            int n_edges, int NB) {
    __shared__ int h[MAXNB];
    __shared__ int base[MAXNB];
    __shared__ int off[MAXNB];
    int nb_blocks = gridDim.x;
    int c0 = (int)((long)n_edges * blockIdx.x / nb_blocks);
    int c1 = (int)((long)n_edges * (blockIdx.x + 1) / nb_blocks);
    for (int i = threadIdx.x; i < NB; i += blockDim.x) { h[i] = 0; off[i] = 0; }
    __syncthreads();
    for (int e = c0 + threadIdx.x; e < c1; e += blockDim.x)
        atomicAdd(&h[rows[e] >> BSH], 1);
    __syncthreads();
    for (int i = threadIdx.x; i < NB; i += blockDim.x)
        if (h[i]) base[i] = atomicAdd(&bfill[i], h[i]);
    __syncthreads();
    for (int e = c0 + threadIdx.x; e < c1; e += blockDim.x) {
        int r = rows[e];
        int b = r >> BSH;
        int pos = base[b] + atomicAdd(&off[b], 1);
        etmp[pos] = ((long)(unsigned)__float_as_int(vals[e]) << 32)
                  | (unsigned)(cols[e] | ((r & (BROWS - 1)) << 20));
    }
}

// ---------- In-bucket counting sort -> exact CSR (R6 single-pass) ----------
__global__ __launch_bounds__(256) void
sort_kernel(const long* __restrict__ etmp, const int* __restrict__ bstart,
            long* __restrict__ edges, int* __restrict__ row_start,
            int* __restrict__ cnt, int N) {
    __shared__ long obuf[SCAP];
    __shared__ int h[BROWS];
    __shared__ int excl[BROWS];
    __shared__ int off[BROWS];
    int b = blockIdx.x;
    int s = bstart[b];
    int t = bstart[b + 1];
    int m = t - s;
    int tid = threadIdx.x;
    if (tid < BROWS) { h[tid] = 0; off[tid] = 0; }
    __syncthreads();
    for (int i = tid; i < m; i += 256)
        atomicAdd(&h[((int)etmp[s + i] >> 20) & (BROWS - 1)], 1);
    __syncthreads();
    if (tid < BROWS) excl[tid] = h[tid];
    __syncthreads();
    for (int o = 1; o < BROWS; o <<= 1) {
        int v = (tid < BROWS && tid >= o) ? excl[tid - o] : 0;
        __syncthreads();
        if (tid < BROWS) excl[tid] += v;
        __syncthreads();
    }
    int row0 = b << BSH;
    if (tid < BROWS) {
        int ex = excl[tid] - h[tid];       // exclusive
        excl[tid] = ex;
        int row = row0 + tid;
        if (row < N) { row_start[row] = s + ex; cnt[row] = h[tid]; }
    }
    __syncthreads();
    if (m <= SCAP) {
        for (int i = tid; i < m; i += 256) {
            long v = etmp[s + i];          // L2-hot second read
            int r = ((int)v >> 20) & (BROWS - 1);
            int pos = excl[r] + atomicAdd(&off[r], 1);
            obuf[pos] = v;
        }
        __syncthreads();
        for (int i = tid; i < m; i += 256) edges[s + i] = obuf[i];
    } else {
        for (int i = tid; i < m; i += 256) {
            long v = etmp[s + i];
            int r = ((int)v >> 20) & (BROWS - 1);
            int pos = s + excl[r] + atomicAdd(&off[r], 1);
            edges[pos] = v;
        }
    }
}

// ---------- Phase 2b: CSR SpMV, one wave per row (full layers) ----------
// Wave-uniform row via readfirstlane -> edge loads scalarize (s_load / K$),
// VMEM pipe free for the 16 outstanding 256B x-row gathers.
__global__ __launch_bounds__(256) void
spmv_kernel(const long* __restrict__ edges, const int* __restrict__ row_start,
            const int* __restrict__ cnt, const float* __restrict__ x,
            float* __restrict__ nxt, float* __restrict__ acc, int N) {
    int wid = (int)((long)blockIdx.x * blockDim.x + threadIdx.x) >> 6;
    int row = __builtin_amdgcn_readfirstlane(wid);
    int lane = threadIdx.x & 63;
    if (row >= N) return;
    int s = __builtin_amdgcn_readfirstlane(row_start[row]);
    int n = __builtin_amdgcn_readfirstlane(cnt[row]);
    const long* ep = edges + s;
    float sum = 0.f;
    int e = 0;
    for (; e + 16 <= n; e += 16) {
        long q[16];
        float g[16];
        #pragma unroll
        for (int j = 0; j < 16; ++j) q[j] = ep[e + j];
        #pragma unroll
        for (int j = 0; j < 16; ++j) g[j] = x[(long)((int)q[j] & 0xFFFFF) * D + lane];
        #pragma unroll
        for (int j = 0; j < 16; ++j) sum += __int_as_float((int)(q[j] >> 32)) * g[j];
    }
    for (; e + 4 <= n; e += 4) {
        long q[4];
        float g[4];
        #pragma unroll
        for (int j = 0; j < 4; ++j) q[j] = ep[e + j];
        #pragma unroll
        for (int j = 0; j < 4; ++j) g[j] = x[(long)((int)q[j] & 0xFFFFF) * D + lane];
        #pragma unroll
        for (int j = 0; j < 4; ++j) sum += __int_as_float((int)(q[j] >> 32)) * g[j];
    }
    for (; e < n; ++e) {
        long q = ep[e];
        sum += __int_as_float((int)(q >> 32)) * x[(long)((int)q & 0xFFFFF) * D + lane];
    }
    long o = (long)row * D + lane;
    if (acc) { nxt[o] = sum; acc[o] += sum; }
    else __builtin_nontemporal_store(sum, &nxt[o]);
}

// ---------- Phase 2c: sparse layer 3 -- wave per LISTED row ----------
__global__ __launch_bounds__(256) void
spmv_list_kernel(const long* __restrict__ edges, const int* __restrict__ row_start,
                 const int* __restrict__ cnt, const int* __restrict__ rowlist,
                 const int* __restrict__ nlist, const float* __restrict__ x,
                 float* __restrict__ nxt, float* __restrict__ acc) {
    int wid = (int)((long)blockIdx.x * blockDim.x + threadIdx.x) >> 6;
    int nl = __builtin_amdgcn_readfirstlane(nlist[0]);
    if (wid >= nl) return;
    int row = __builtin_amdgcn_readfirstlane(rowlist[wid]);
    int lane = threadIdx.x & 63;
    int s = __builtin_amdgcn_readfirstlane(row_start[row]);
    int n = __builtin_amdgcn_readfirstlane(cnt[row]);
    const long* ep = edges + s;
    float sum = 0.f;
    int e = 0;
    for (; e + 16 <= n; e += 16) {
        long q[16];
        float g[16];
        #pragma unroll
        for (int j = 0; j < 16; ++j) q[j] = ep[e + j];
        #pragma unroll
        for (int j = 0; j < 16; ++j) g[j] = x[(long)((int)q[j] & 0xFFFFF) * D + lane];
        #pragma unroll
        for (int j = 0; j < 16; ++j) sum += __int_as_float((int)(q[j] >> 32)) * g[j];
    }
    for (; e + 4 <= n; e += 4) {
        long q[4];
        float g[4];
        #pragma unroll
        for (int j = 0; j < 4; ++j) q[j] = ep[e + j];
        #pragma unroll
        for (int j = 0; j < 4; ++j) g[j] = x[(long)((int)q[j] & 0xFFFFF) * D + lane];
        #pragma unroll
        for (int j = 0; j < 4; ++j) sum += __int_as_float((int)(q[j] >> 32)) * g[j];
    }
    for (; e < n; ++e) {
        long q = ep[e];
        sum += __int_as_float((int)(q >> 32)) * x[(long)((int)q & 0xFFFFF) * D + lane];
    }
    long o = (long)row * D + lane;
    if (acc) { nxt[o] = sum; acc[o] += sum; }
    else __builtin_nontemporal_store(sum, &nxt[o]);
}

// ---------- Phase 3: gamma = dot of layer-mean embeddings ----------
__global__ void dot_kernel(const float* __restrict__ x0, const float* __restrict__ x1,
                           const float* __restrict__ x2, const float* __restrict__ x3,
                           const float* __restrict__ acc,
                           const int* __restrict__ users, const int* __restrict__ items,
                           float* __restrict__ out, int U, int B) {
    int wave = (blockIdx.x * blockDim.x + threadIdx.x) >> 6;
    int lane = threadIdx.x & 63;
    if (wave >= B) return;
    long ou = (long)users[wave] * D + lane;
    long oi = (long)(U + items[wave]) * D + lane;
    float su, si;
    if (acc) {
        su = acc[ou];
        si = acc[oi];
    } else {
        su = x0[ou] + x1[ou] + x2[ou] + x3[ou];
        si = x0[oi] + x1[oi] + x2[oi] + x3[oi];
    }
    float p = su * si;
    #pragma unroll
    for (int off = 32; off > 0; off >>= 1) p += __shfl_xor(p, off, 64);
    if (lane == 0) out[wave] = p * 0.0625f;
}

extern "C" void kernel_launch(void* const* d_in, const int* in_sizes, int n_in,
                              void* d_out, int out_size, void* d_ws, size_t ws_size,
                              hipStream_t stream) {
    const int*   users    = (const int*)  d_in[0];
    const int*   items    = (const int*)  d_in[1];
    const int*   g_rows   = (const int*)  d_in[2];
    const int*   g_cols   = (const int*)  d_in[3];
    const float* g_vals   = (const float*)d_in[4];
    const float* user_emb = (const float*)d_in[5];
    const float* item_emb = (const float*)d_in[6];
    const float* ent_emb  = (const float*)d_in[7];
    const float* rel_emb  = (const float*)d_in[8];
    const int*   kg_e     = (const int*)  d_in[9];
    const int*   kg_r     = (const int*)  d_in[10];
    const float* fc_W     = (const float*)d_in[11];
    const float* fc_b     = (const float*)d_in[12];
    float* out = (float*)d_out;

    int B       = in_sizes[0];
    int n_edges = in_sizes[2];
    int U       = in_sizes[5] / D;
    int I       = in_sizes[6] / D;
    int NE1     = in_sizes[7] / D;   // E_ENT + 1
    int NR      = in_sizes[8] / D;   // R + 1
    int K       = in_sizes[9] / I;
    int N  = U + I;
    int ND = N * D;
    int NB = (N + BROWS - 1) >> BSH;   // 1172 buckets (<= MAXNB)

    // deferred-acc mode needs 4 layer buffers; legacy needs 3 (x,y,acc)
    size_t small = (size_t)(2 * NR * D + NR + 3 * (NB + 1) + 4 * N + 1) * 4 + 8192;
    size_t need_def = 4ul * ND * 4 + (size_t)n_edges * 8 + small;
    int deferred = (need_def <= ws_size);

    char* basep = (char*)d_ws;
    size_t woff = 0;
    auto alloc = [&](size_t bytes) -> char* {
        char* p = basep + woff;
        woff = (woff + bytes + 255) & ~(size_t)255;
        return p;
    };

    float *x0, *x1, *x2, *x3, *acc;
    long* etmp;
    if (deferred) {
        x0 = (float*)alloc((size_t)ND * 4);
        x1 = (float*)alloc((size_t)ND * 4);
        x2 = (float*)alloc((size_t)ND * 4);
        x3 = (float*)alloc((size_t)ND * 4);
        acc = nullptr;
        etmp = (long*)x2;               // x2+x3 span 38.4MB >= 32MB; build precedes layers
    } else {
        x0 = (float*)alloc((size_t)ND * 4);
        x1 = (float*)alloc((size_t)ND * 4);
        x2 = x0; x3 = x1;               // ping-pong
        acc = (float*)alloc((size_t)ND * 4);
        etmp = (long*)x0;               // x0+x1 span
    }
    float* w1r      = (float*)alloc((size_t)NR * D * 4);
    float* w2r      = (float*)alloc((size_t)NR * D * 4);
    float* br       = (float*)alloc((size_t)NR * 4);
    int*   bcnt     = (int*)  alloc((size_t)(NB + 1) * 4);
    int*   bstart   = (int*)  alloc((size_t)(NB + 1) * 4);
    int*   bfill    = (int*)  alloc((size_t)(NB + 1) * 4);
    int*   row_start= (int*)  alloc((size_t)N * 4);
    int*   cnt      = (int*)  alloc((size_t)N * 4);
    int*   flags    = (int*)  alloc((size_t)(N + 1) * 4);  // +1: nlist counter
    int*   rowlist  = (int*)  alloc((size_t)N * 4);
    int*   nlist    = flags + N;
    long*  edges    = (long*) alloc((size_t)n_edges * 8);

    // ---- CSR build (etmp occupies layer-buffer space; runs first) ----
    hipMemsetAsync(bcnt, 0, (size_t)(NB + 1) * 4, stream);
    bhist_kernel<<<512, 256, 0, stream>>>(g_rows, bcnt, n_edges, NB);
    bscan_kernel<<<1, 1024, 0, stream>>>(bcnt, bstart, bfill, NB, n_edges);
    part_kernel<<<512, 256, 0, stream>>>(g_rows, g_cols, g_vals, bfill, etmp, n_edges, NB);
    sort_kernel<<<NB, 256, 0, stream>>>(etmp, bstart, edges, row_start, cnt, N);

    // ---- batch-row compaction for sparse layer 3 ----
    hipMemsetAsync(flags, 0, (size_t)(N + 1) * 4, stream);
    mark_kernel<<<(B + 255) / 256, 256, 0, stream>>>(users, items, flags, rowlist, nlist, U, B);

    // Phase 0 + 1: GAT
    relpre_kernel<<<NR, D, 0, stream>>>(fc_W, fc_b, rel_emb, w1r, w2r, br);
    if (K == 16) {
        gat16_kernel<<<(I + 3) / 4, 256, 0, stream>>>(item_emb, ent_emb, kg_e, kg_r,
                                                      w1r, w2r, br,
                                                      x0 + (long)U * D, I, NE1 - 1);
    } else {
        gat_kernel<<<(I + 3) / 4, 256, 0, stream>>>(item_emb, ent_emb, kg_e, kg_r,
                                                    w1r, w2r, br,
                                                    x0 + (long)U * D, I, K, NE1 - 1);
    }

    // Phase 2a: user half of x0 (+ acc init in legacy mode)
    if (deferred) {
        int n4 = U * D / 4;
        copyu_kernel<<<(n4 + 255) / 256, 256, 0, stream>>>(user_emb, x0, n4);
    } else {
        init_kernel<<<2048, 256, 0, stream>>>(user_emb, x0, acc, U * D, ND);
    }

    // Phase 2b: layers 1-2 full (wave per row)
    long total = (long)N * 64;
    int blocks = (int)((total + 255) / 256);
    spmv_kernel<<<blocks, 256, 0, stream>>>(edges, row_start, cnt, x0, x1, acc, N);
    spmv_kernel<<<blocks, 256, 0, stream>>>(edges, row_start, cnt, x1, x2, acc, N);

    // Phase 2c: layer 3 sparse -- only unique batch rows (<= min(2B, N))
    int maxrows = (2 * B < N) ? 2 * B : N;
    int lblocks = (int)(((long)maxrows * 64 + 255) / 256);
    spmv_list_kernel<<<lblocks, 256, 0, stream>>>(edges, row_start, cnt, rowlist, nlist,
                                                  x2, x3, acc);

    // Phase 3: batch dot
    dot_kernel<<<(B + 3) / 4, 256, 0, stream>>>(x0, x1, x2, x3, acc, users, items, out, U, B);
}